// Round 1
// baseline (877.255 us; speedup 1.0000x reference)
//
#include <hip/hip_runtime.h>
#include <stdint.h>

#define NUM_CLASSES 80u
#define TOPK 1000
#define CONF_T 0.05f
#define NMS_T 0.6f
#define MAX_COORD 4096.0f
#define TARGET 1152u      // top-1000 + tie/superset slack
#define CAP 49152u        // candidate buffer capacity (coarse-threshold pass)
#define SORTN 4096        // bitonic sort width (LDS)

// Monotone float->uint key: descending float == descending key
__device__ __forceinline__ uint32_t fkey(float x) {
  uint32_t k = __float_as_uint(x);
  return (k & 0x80000000u) ? ~k : (k | 0x80000000u);
}

// ---------------- kernel Z: zero hist + counters (ws is poisoned 0xAA) ----
__global__ void kz(uint32_t* histC, uint32_t* sel) {
  int t = threadIdx.x;
  if (t < 1024) histC[t] = 0u;
  if (t < 16) sel[t] = 0u;
}

// ---------------- kernel A: coarse 1024-bin histogram of key>>22 ----------
__global__ void kA(const float4* __restrict__ cls, int n4, uint32_t* histC) {
  __shared__ uint32_t h[1024];
  for (int i = threadIdx.x; i < 1024; i += blockDim.x) h[i] = 0u;
  __syncthreads();
  int stride = gridDim.x * blockDim.x;
  for (int i = blockIdx.x * blockDim.x + threadIdx.x; i < n4; i += stride) {
    float4 v = cls[i];
    atomicAdd(&h[fkey(v.x) >> 22], 1u);
    atomicAdd(&h[fkey(v.y) >> 22], 1u);
    atomicAdd(&h[fkey(v.z) >> 22], 1u);
    atomicAdd(&h[fkey(v.w) >> 22], 1u);
  }
  __syncthreads();
  for (int i = threadIdx.x; i < 1024; i += blockDim.x)
    if (h[i]) atomicAdd(&histC[i], h[i]);
}

// ---------------- kernel B: pick coarse bin (suffix count >= TARGET) ------
__global__ void kB(const uint32_t* __restrict__ histC, uint32_t* sel) {
  if (threadIdx.x == 0 && blockIdx.x == 0) {
    uint32_t cum = 0u;
    for (int b = 1023; b >= 0; --b) {
      uint32_t c = histC[b];
      if (cum + c >= TARGET) { sel[0] = (uint32_t)b; sel[1] = cum; return; }
      cum += c;
    }
    sel[0] = 0u; sel[1] = 0u;
  }
}

// ---------------- kernel E: compact candidates with key>>22 >= bin --------
__global__ void kE(const float4* __restrict__ cls, int n4,
                   uint32_t* sel, uint32_t* candKey, uint32_t* candIdx) {
  uint32_t bsel = sel[0];
  int stride = gridDim.x * blockDim.x;
  for (int i = blockIdx.x * blockDim.x + threadIdx.x; i < n4; i += stride) {
    float4 v = cls[i];
    float c4[4] = {v.x, v.y, v.z, v.w};
#pragma unroll
    for (int c = 0; c < 4; ++c) {
      uint32_t key = fkey(c4[c]);
      if ((key >> 22) >= bsel) {
        uint32_t pos = atomicAdd(&sel[2], 1u);  // compiler wave-aggregates
        if (pos < CAP) { candKey[pos] = key; candIdx[pos] = (uint32_t)i * 4u + c; }
      }
    }
  }
}

// ---------------- kernel F: refine + sigmoid + bitonic sort + emit --------
__global__ void __launch_bounds__(1024) kF(
    const float* __restrict__ cls, const float* __restrict__ box,
    const int* __restrict__ ph, const int* __restrict__ pw,
    const uint32_t* __restrict__ sel,
    const uint32_t* __restrict__ candKey, const uint32_t* __restrict__ candIdx,
    float* __restrict__ out, float* __restrict__ topScore, float* __restrict__ obox) {
  __shared__ uint32_t fh[1024];
  __shared__ unsigned long long skey[SORTN];
  __shared__ uint32_t scount;
  __shared__ uint32_t TkeyS;
  int tid = threadIdx.x;
  uint32_t n = sel[2]; if (n > CAP) n = CAP;
  uint32_t bsel = sel[0], above = sel[1];

  for (int i = tid; i < 1024; i += 1024) fh[i] = 0u;
  for (int i = tid; i < SORTN; i += 1024) skey[i] = 0ull;
  if (tid == 0) scount = 0u;
  __syncthreads();

  // fine histogram of next 10 key bits inside the boundary coarse bin
  for (uint32_t i = tid; i < n; i += 1024u) {
    uint32_t k = candKey[i];
    if ((k >> 22) == bsel) atomicAdd(&fh[(k >> 12) & 1023u], 1u);
  }
  __syncthreads();
  if (tid == 0) {
    uint32_t cum = above; int s = 1023;
    for (; s >= 0; --s) { cum += fh[s]; if (cum >= TARGET) break; }
    if (s < 0) s = 0;
    TkeyS = (bsel << 22) | ((uint32_t)s << 12);
  }
  __syncthreads();
  uint32_t T = TkeyS;

  // select survivors, compute fp32 sigmoid (replicating np 1/(1+exp(-x)))
  for (uint32_t i = tid; i < n; i += 1024u) {
    uint32_t k = candKey[i];
    if (k >= T) {
      uint32_t pos = atomicAdd(&scount, 1u);
      if (pos < SORTN) {
        uint32_t idx = candIdx[i];
        float x = cls[idx];
        float p = 1.0f / (1.0f + expf(-x));
        skey[pos] = ((unsigned long long)__float_as_uint(p) << 32) |
                    (unsigned long long)(uint32_t)(~idx);  // ties: lower idx first
      }
    }
  }
  __syncthreads();

  // bitonic sort, descending by (p_bits, ~idx)
  for (int size = 2; size <= SORTN; size <<= 1) {
    for (int stride = size >> 1; stride > 0; stride >>= 1) {
      __syncthreads();
      for (int t = tid; t < SORTN / 2; t += 1024) {
        int lo = t & (stride - 1);
        int i = ((t - lo) << 1) | lo;
        int j = i + stride;
        unsigned long long a = skey[i], b = skey[j];
        bool desc = ((i & size) == 0);
        if (desc ? (a < b) : (a > b)) { skey[i] = b; skey[j] = a; }
      }
    }
  }
  __syncthreads();

  float W = (float)pw[0], H = (float)ph[0];
  for (int r = tid; r < TOPK; r += 1024) {
    unsigned long long k = skey[r];
    uint32_t idx; float p;
    if (k == 0ull) { idx = 0u; p = 0.0f; }
    else { idx = ~(uint32_t)k; p = __uint_as_float((uint32_t)(k >> 32)); }
    uint32_t label = idx % NUM_CLASSES;
    uint32_t anchor = idx / NUM_CLASSES;
    float b0 = box[anchor * 4u + 0u], b1 = box[anchor * 4u + 1u];
    float b2 = box[anchor * 4u + 2u], b3 = box[anchor * 4u + 3u];
    out[r * 4 + 0] = fminf(fmaxf(b0 / W, 0.0f), 1.0f);
    out[r * 4 + 1] = fminf(fmaxf(b1 / H, 0.0f), 1.0f);
    out[r * 4 + 2] = fminf(fmaxf(b2 / W, 0.0f), 1.0f);
    out[r * 4 + 3] = fminf(fmaxf(b3 / H, 0.0f), 1.0f);
    out[5000 + r] = (float)label;
    topScore[r] = p;
    float off = (float)label * MAX_COORD;  // class-aware NMS offset
    obox[r * 4 + 0] = b0 + off; obox[r * 4 + 1] = b1 + off;
    obox[r * 4 + 2] = b2 + off; obox[r * 4 + 3] = b3 + off;
  }
}

// ---------------- kernel G: IoU suppression bitmasks (j > i) --------------
__global__ void kG(const float* __restrict__ obox, unsigned long long* __restrict__ masks) {
  int i = blockIdx.x;  // row 0..999
  float x1i = obox[i * 4 + 0], y1i = obox[i * 4 + 1];
  float x2i = obox[i * 4 + 2], y2i = obox[i * 4 + 3];
  float ai = (x2i - x1i) * (y2i - y1i);
  for (int base = 0; base < 1024; base += 256) {
    int jj = base + (int)threadIdx.x;
    bool bit = false;
    if (jj < TOPK && jj > i) {
      float x1j = obox[jj * 4 + 0], y1j = obox[jj * 4 + 1];
      float x2j = obox[jj * 4 + 2], y2j = obox[jj * 4 + 3];
      float aj = (x2j - x1j) * (y2j - y1j);
      float ix1 = fmaxf(x1i, x1j), iy1 = fmaxf(y1i, y1j);
      float ix2 = fminf(x2i, x2j), iy2 = fminf(y2i, y2j);
      float iw = fmaxf(ix2 - ix1, 0.0f), ih = fmaxf(iy2 - iy1, 0.0f);
      float inter = iw * ih;
      float iou = inter / (ai + aj - inter + 1e-9f);
      bit = iou > NMS_T;
    }
    unsigned long long m = __ballot(bit);
    if ((threadIdx.x & 63u) == 0u) masks[i * 16 + (jj >> 6)] = m;
  }
}

// ---------------- kernel H: sequential greedy NMS + final outputs ---------
__global__ void __launch_bounds__(64) kH(const float* __restrict__ topScore,
                                         const unsigned long long* __restrict__ masks,
                                         float* __restrict__ out) {
  __shared__ unsigned long long keepw[16];
  int t = threadIdx.x;
  if (t < 16) {
    unsigned long long w = 0ull;
    for (int b = 0; b < 64; ++b) {
      int r = t * 64 + b;
      if (r < TOPK && topScore[r] > CONF_T) w |= (1ull << b);
    }
    keepw[t] = w;
  }
  __syncthreads();
  for (int i = 0; i < TOPK; ++i) {
    unsigned long long kw = keepw[i >> 6];
    if ((kw >> (i & 63)) & 1ull) {
      if (t < 16) keepw[t] &= ~masks[i * 16 + t];
    }
    __syncthreads();
  }
  for (int r = t; r < TOPK; r += 64) {
    bool k = (keepw[r >> 6] >> (r & 63)) & 1ull;
    float s = topScore[r];
    out[4000 + r] = k ? s : 0.0f;
    out[6000 + r] = k ? 1.0f : 0.0f;
  }
}

extern "C" void kernel_launch(void* const* d_in, const int* in_sizes, int n_in,
                              void* d_out, int out_size, void* d_ws, size_t ws_size,
                              hipStream_t stream) {
  const float* cls = (const float*)d_in[0];  // (1, N, 80) logits
  const float* box = (const float*)d_in[1];  // (1, N, 4)
  const int* ph = (const int*)d_in[2];       // img_h = 1024
  const int* pw = (const int*)d_in[3];       // img_w = 1024
  float* out = (float*)d_out;                // [boxes 4000 | scores 1000 | labels 1000 | keep 1000]
  int n = in_sizes[0];                       // 20,971,520 (divisible by 4)

  uint8_t* w = (uint8_t*)d_ws;
  uint32_t* histC   = (uint32_t*)(w);                          // 4 KB
  uint32_t* sel     = (uint32_t*)(w + 4096);                   // 64 B
  uint32_t* candKey = (uint32_t*)(w + 8192);                   // CAP*4
  uint32_t* candIdx = (uint32_t*)(w + 8192 + (size_t)CAP * 4); // CAP*4
  float*    topScore= (float*)   (w + 8192 + (size_t)CAP * 8);         // 4 KB
  float*    obox    = (float*)   (w + 8192 + (size_t)CAP * 8 + 4096);  // 16 KB
  unsigned long long* masks = (unsigned long long*)
                             (w + 8192 + (size_t)CAP * 8 + 4096 + 16384); // 125 KB

  kz<<<1, 1024, 0, stream>>>(histC, sel);
  kA<<<2048, 256, 0, stream>>>((const float4*)cls, n / 4, histC);
  kB<<<1, 64, 0, stream>>>(histC, sel);
  kE<<<2048, 256, 0, stream>>>((const float4*)cls, n / 4, sel, candKey, candIdx);
  kF<<<1, 1024, 0, stream>>>(cls, box, ph, pw, sel, candKey, candIdx, out, topScore, obox);
  kG<<<TOPK, 256, 0, stream>>>(obox, masks);
  kH<<<1, 64, 0, stream>>>(topScore, masks, out);
}

// Round 2
// 364.084 us; speedup vs baseline: 2.4095x; 2.4095x over previous
//
#include <hip/hip_runtime.h>
#include <stdint.h>

#define NUM_CLASSES 80u
#define TOPK 1000
#define CONF_T 0.05f
#define NMS_T 0.6f
#define MAX_COORD 4096.0f
#define TARGET 1152u      // top-1000 + tie/superset slack
#define CAP 49152u        // candidate buffer capacity (coarse-threshold pass)
#define SORTN 4096        // bitonic sort width (LDS)
#define NBINS 4096        // coarse bins = key >> 20 (12 bits)

// Monotone float->uint key: descending float == descending key
__device__ __forceinline__ uint32_t fkey(float x) {
  uint32_t k = __float_as_uint(x);
  return (k & 0x80000000u) ? ~k : (k | 0x80000000u);
}

// ---------------- kernel Z: zero hist + counters (ws is poisoned 0xAA) ----
__global__ void kz(uint32_t* histC, uint32_t* sel) {
  int t = threadIdx.x;
  for (int i = t; i < NBINS; i += 1024) histC[i] = 0u;
  if (t < 16) sel[t] = 0u;
}

// ---------------- kernel A: coarse 4096-bin histogram of key>>20 ----------
// 2 interleaved LDS copies (h[bin*2 | tid&1]) to cut same-address atomic
// contention; 12-bit bins spread each hot exponent over 8 mantissa sub-bins.
__global__ void __launch_bounds__(256) kA(const float4* __restrict__ cls, int n4,
                                          uint32_t* histC) {
  __shared__ uint32_t h[NBINS * 2];
  for (int i = threadIdx.x; i < NBINS * 2; i += 256) h[i] = 0u;
  __syncthreads();
  uint32_t sub = threadIdx.x & 1u;
  int stride = gridDim.x * blockDim.x;
  for (int i = blockIdx.x * blockDim.x + threadIdx.x; i < n4; i += stride) {
    float4 v = cls[i];
    atomicAdd(&h[((fkey(v.x) >> 20) << 1) | sub], 1u);
    atomicAdd(&h[((fkey(v.y) >> 20) << 1) | sub], 1u);
    atomicAdd(&h[((fkey(v.z) >> 20) << 1) | sub], 1u);
    atomicAdd(&h[((fkey(v.w) >> 20) << 1) | sub], 1u);
  }
  __syncthreads();
  for (int i = threadIdx.x; i < NBINS; i += 256) {
    uint32_t c = h[i * 2] + h[i * 2 + 1];
    if (c) atomicAdd(&histC[i], c);
  }
}

// ---------------- kernel B: pick coarse bin (suffix count >= TARGET) ------
__global__ void kB(const uint32_t* __restrict__ histC, uint32_t* sel) {
  if (threadIdx.x == 0 && blockIdx.x == 0) {
    uint32_t cum = 0u;
    for (int b = NBINS - 1; b >= 0; --b) {
      uint32_t c = histC[b];
      if (cum + c >= TARGET) { sel[0] = (uint32_t)b; sel[1] = cum; return; }
      cum += c;
    }
    sel[0] = 0u; sel[1] = 0u;
  }
}

// ---------------- kernel E: compact candidates with key>>20 >= bin --------
__global__ void kE(const float4* __restrict__ cls, int n4,
                   uint32_t* sel, uint32_t* candKey, uint32_t* candIdx) {
  uint32_t bsel = sel[0];
  int stride = gridDim.x * blockDim.x;
  for (int i = blockIdx.x * blockDim.x + threadIdx.x; i < n4; i += stride) {
    float4 v = cls[i];
    float c4[4] = {v.x, v.y, v.z, v.w};
#pragma unroll
    for (int c = 0; c < 4; ++c) {
      uint32_t key = fkey(c4[c]);
      if ((key >> 20) >= bsel) {
        uint32_t pos = atomicAdd(&sel[2], 1u);  // compiler wave-aggregates
        if (pos < CAP) { candKey[pos] = key; candIdx[pos] = (uint32_t)i * 4u + c; }
      }
    }
  }
}

// ---------------- kernel F: refine + sigmoid + bitonic sort + emit --------
__global__ void __launch_bounds__(1024) kF(
    const float* __restrict__ cls, const float* __restrict__ box,
    const int* __restrict__ ph, const int* __restrict__ pw,
    const uint32_t* __restrict__ sel,
    const uint32_t* __restrict__ candKey, const uint32_t* __restrict__ candIdx,
    float* __restrict__ out, float* __restrict__ topScore, float* __restrict__ obox) {
  __shared__ uint32_t fh[1024];
  __shared__ unsigned long long skey[SORTN];
  __shared__ uint32_t scount;
  __shared__ uint32_t TkeyS;
  int tid = threadIdx.x;
  uint32_t n = sel[2]; if (n > CAP) n = CAP;
  uint32_t bsel = sel[0], above = sel[1];

  for (int i = tid; i < 1024; i += 1024) fh[i] = 0u;
  for (int i = tid; i < SORTN; i += 1024) skey[i] = 0ull;
  if (tid == 0) scount = 0u;
  __syncthreads();

  // fine histogram of next 10 key bits (19..10) inside the boundary bin
  for (uint32_t i = tid; i < n; i += 1024u) {
    uint32_t k = candKey[i];
    if ((k >> 20) == bsel) atomicAdd(&fh[(k >> 10) & 1023u], 1u);
  }
  __syncthreads();
  if (tid == 0) {
    uint32_t cum = above; int s = 1023;
    for (; s >= 0; --s) { cum += fh[s]; if (cum >= TARGET) break; }
    if (s < 0) s = 0;
    TkeyS = (bsel << 20) | ((uint32_t)s << 10);
  }
  __syncthreads();
  uint32_t T = TkeyS;

  // select survivors, compute fp32 sigmoid (replicating np 1/(1+exp(-x)))
  for (uint32_t i = tid; i < n; i += 1024u) {
    uint32_t k = candKey[i];
    if (k >= T) {
      uint32_t pos = atomicAdd(&scount, 1u);
      if (pos < SORTN) {
        uint32_t idx = candIdx[i];
        float x = cls[idx];
        float p = 1.0f / (1.0f + expf(-x));
        skey[pos] = ((unsigned long long)__float_as_uint(p) << 32) |
                    (unsigned long long)(uint32_t)(~idx);  // ties: lower idx first
      }
    }
  }
  __syncthreads();

  // bitonic sort, descending by (p_bits, ~idx)
  for (int size = 2; size <= SORTN; size <<= 1) {
    for (int stride = size >> 1; stride > 0; stride >>= 1) {
      __syncthreads();
      for (int t = tid; t < SORTN / 2; t += 1024) {
        int lo = t & (stride - 1);
        int i = ((t - lo) << 1) | lo;
        int j = i + stride;
        unsigned long long a = skey[i], b = skey[j];
        bool desc = ((i & size) == 0);
        if (desc ? (a < b) : (a > b)) { skey[i] = b; skey[j] = a; }
      }
    }
  }
  __syncthreads();

  float W = (float)pw[0], H = (float)ph[0];
  for (int r = tid; r < TOPK; r += 1024) {
    unsigned long long k = skey[r];
    uint32_t idx; float p;
    if (k == 0ull) { idx = 0u; p = 0.0f; }
    else { idx = ~(uint32_t)k; p = __uint_as_float((uint32_t)(k >> 32)); }
    uint32_t label = idx % NUM_CLASSES;
    uint32_t anchor = idx / NUM_CLASSES;
    float b0 = box[anchor * 4u + 0u], b1 = box[anchor * 4u + 1u];
    float b2 = box[anchor * 4u + 2u], b3 = box[anchor * 4u + 3u];
    out[r * 4 + 0] = fminf(fmaxf(b0 / W, 0.0f), 1.0f);
    out[r * 4 + 1] = fminf(fmaxf(b1 / H, 0.0f), 1.0f);
    out[r * 4 + 2] = fminf(fmaxf(b2 / W, 0.0f), 1.0f);
    out[r * 4 + 3] = fminf(fmaxf(b3 / H, 0.0f), 1.0f);
    out[5000 + r] = (float)label;
    topScore[r] = p;
    float off = (float)label * MAX_COORD;  // class-aware NMS offset
    obox[r * 4 + 0] = b0 + off; obox[r * 4 + 1] = b1 + off;
    obox[r * 4 + 2] = b2 + off; obox[r * 4 + 3] = b3 + off;
  }
}

// ---------------- kernel G: IoU suppression bitmasks (j > i) --------------
__global__ void kG(const float* __restrict__ obox, unsigned long long* __restrict__ masks) {
  int i = blockIdx.x;  // row 0..999
  float x1i = obox[i * 4 + 0], y1i = obox[i * 4 + 1];
  float x2i = obox[i * 4 + 2], y2i = obox[i * 4 + 3];
  float ai = (x2i - x1i) * (y2i - y1i);
  for (int base = 0; base < 1024; base += 256) {
    int jj = base + (int)threadIdx.x;
    bool bit = false;
    if (jj < TOPK && jj > i) {
      float x1j = obox[jj * 4 + 0], y1j = obox[jj * 4 + 1];
      float x2j = obox[jj * 4 + 2], y2j = obox[jj * 4 + 3];
      float aj = (x2j - x1j) * (y2j - y1j);
      float ix1 = fmaxf(x1i, x1j), iy1 = fmaxf(y1i, y1j);
      float ix2 = fminf(x2i, x2j), iy2 = fminf(y2i, y2j);
      float iw = fmaxf(ix2 - ix1, 0.0f), ih = fmaxf(iy2 - iy1, 0.0f);
      float inter = iw * ih;
      float iou = inter / (ai + aj - inter + 1e-9f);
      bit = iou > NMS_T;
    }
    unsigned long long m = __ballot(bit);
    if ((threadIdx.x & 63u) == 0u) masks[i * 16 + (jj >> 6)] = m;
  }
}

// ---------------- kernel H: LDS-staged single-wave greedy NMS -------------
// Masks staged to LDS (128 KB) in parallel; greedy loop runs on wave 0 with
// keep words in registers (lanes 0..15) and skips rows with empty masks.
__global__ void __launch_bounds__(256) kH(const float* __restrict__ topScore,
                                          const unsigned long long* __restrict__ masks,
                                          float* __restrict__ out) {
  __shared__ unsigned long long lmask[TOPK * 16];
  __shared__ uint32_t nzrow[TOPK];
  __shared__ unsigned long long keepsh[16];
  int t = threadIdx.x;
  for (int i = t; i < TOPK; i += 256) nzrow[i] = 0u;
  if (t < 16) keepsh[t] = 0ull;
  __syncthreads();
  // stage masks (coalesced) + flag nonzero rows
  for (int i = t; i < TOPK * 16; i += 256) {
    unsigned long long m = masks[i];
    lmask[i] = m;
    if (m) atomicOr(&nzrow[i >> 4], 1u);
  }
  // init keep bits from scores via ballot (4 waves cover 256 rows/iter)
  for (int base = 0; base < 1024; base += 256) {
    int r = base + t;
    bool v = (r < TOPK) && (topScore[r] > CONF_T);
    unsigned long long b = __ballot(v);
    if ((t & 63) == 0) keepsh[(base >> 6) + (t >> 6)] = b;
  }
  __syncthreads();
  if (t < 64) {  // single-wave greedy loop, no barriers inside
    unsigned long long kw = (t < 16) ? keepsh[t] : 0ull;
    unsigned long long nzw = 0ull;
    if (t < 16) {
      for (int b = 0; b < 64; ++b) {
        int r = t * 64 + b;
        if (r < TOPK && nzrow[r]) nzw |= 1ull << b;
      }
    }
    for (int w = 0; w < 16; ++w) {
      unsigned long long cur = __shfl(kw, w) & __shfl(nzw, w);
      while (cur) {
        int b = __ffsll((long long)cur) - 1;
        int i = w * 64 + b;
        if (t < 16) kw &= ~lmask[i * 16 + t];  // row i suppresses only j > i
        unsigned long long nk = __shfl(kw, w);
        cur = nk & __shfl(nzw, w);
        cur &= (b == 63) ? 0ull : (~0ull << (b + 1));
      }
    }
    if (t < 16) keepsh[t] = kw;
  }
  __syncthreads();
  for (int r = t; r < TOPK; r += 256) {
    bool k = (keepsh[r >> 6] >> (r & 63)) & 1ull;
    float s = topScore[r];
    out[4000 + r] = k ? s : 0.0f;
    out[6000 + r] = k ? 1.0f : 0.0f;
  }
}

extern "C" void kernel_launch(void* const* d_in, const int* in_sizes, int n_in,
                              void* d_out, int out_size, void* d_ws, size_t ws_size,
                              hipStream_t stream) {
  const float* cls = (const float*)d_in[0];  // (1, N, 80) logits
  const float* box = (const float*)d_in[1];  // (1, N, 4)
  const int* ph = (const int*)d_in[2];       // img_h = 1024
  const int* pw = (const int*)d_in[3];       // img_w = 1024
  float* out = (float*)d_out;                // [boxes 4000 | scores 1000 | labels 1000 | keep 1000]
  int n = in_sizes[0];                       // 20,971,520 (divisible by 4)

  uint8_t* w = (uint8_t*)d_ws;
  uint32_t* histC   = (uint32_t*)(w);                          // 16 KB
  uint32_t* sel     = (uint32_t*)(w + 16384);                  // 64 B
  uint32_t* candKey = (uint32_t*)(w + 20480);                  // CAP*4
  uint32_t* candIdx = (uint32_t*)(w + 20480 + (size_t)CAP * 4);
  float*    topScore= (float*)   (w + 20480 + (size_t)CAP * 8);          // 4 KB
  float*    obox    = (float*)   (w + 20480 + (size_t)CAP * 8 + 4096);   // 16 KB
  unsigned long long* masks = (unsigned long long*)
                             (w + 20480 + (size_t)CAP * 8 + 4096 + 16384); // 128 KB

  kz<<<1, 1024, 0, stream>>>(histC, sel);
  kA<<<2048, 256, 0, stream>>>((const float4*)cls, n / 4, histC);
  kB<<<1, 64, 0, stream>>>(histC, sel);
  kE<<<2048, 256, 0, stream>>>((const float4*)cls, n / 4, sel, candKey, candIdx);
  kF<<<1, 1024, 0, stream>>>(cls, box, ph, pw, sel, candKey, candIdx, out, topScore, obox);
  kG<<<TOPK, 256, 0, stream>>>(obox, masks);
  kH<<<1, 256, 0, stream>>>(topScore, masks, out);
}

// Round 3
// 269.962 us; speedup vs baseline: 3.2495x; 1.3486x over previous
//
#include <hip/hip_runtime.h>
#include <stdint.h>

#define NUM_CLASSES 80u
#define TOPK 1000
#define CONF_T 0.05f
#define NMS_T 0.6f
#define MAX_COORD 4096.0f
#define TARGET 1152u      // top-1000 + tie/superset slack
#define CAP 49152u        // candidate buffer capacity (coarse-threshold pass)
#define SORTN 4096        // bitonic sort width (LDS)
#define NBINS 4096        // coarse bins = key >> 20 (12 bits)

// Monotone float->uint key: descending float == descending key
__device__ __forceinline__ uint32_t fkey(float x) {
  uint32_t k = __float_as_uint(x);
  return (k & 0x80000000u) ? ~k : (k | 0x80000000u);
}

// ---------------- kernel Z: zero hist + counters (ws is poisoned 0xAA) ----
__global__ void kz(uint32_t* histC, uint32_t* sel) {
  int t = threadIdx.x;
  for (int i = t; i < NBINS; i += 1024) histC[i] = 0u;
  if (t < 16) sel[t] = 0u;
}

// ---------------- kernel A: histogram of key>>20, positives only ----------
// Only x >= +0 (key >= 0x80000000, bin >= 2048) is histogrammed: ~16% of
// values -> 6x fewer LDS atomics (atomic-issue was the bottleneck). kB
// clamps at bin 2048, so low bins are never consulted.
__global__ void __launch_bounds__(256) kA(const float4* __restrict__ cls, int n4,
                                          uint32_t* histC) {
  __shared__ uint32_t h[NBINS * 2];
  for (int i = threadIdx.x; i < NBINS * 2; i += 256) h[i] = 0u;
  __syncthreads();
  uint32_t sub = threadIdx.x & 1u;
  int stride = gridDim.x * blockDim.x;
  for (int i = blockIdx.x * blockDim.x + threadIdx.x; i < n4; i += stride) {
    float4 v = cls[i];
    uint32_t k0 = fkey(v.x), k1 = fkey(v.y), k2 = fkey(v.z), k3 = fkey(v.w);
    if (k0 & 0x80000000u) atomicAdd(&h[((k0 >> 20) << 1) | sub], 1u);
    if (k1 & 0x80000000u) atomicAdd(&h[((k1 >> 20) << 1) | sub], 1u);
    if (k2 & 0x80000000u) atomicAdd(&h[((k2 >> 20) << 1) | sub], 1u);
    if (k3 & 0x80000000u) atomicAdd(&h[((k3 >> 20) << 1) | sub], 1u);
  }
  __syncthreads();
  for (int i = threadIdx.x; i < NBINS; i += 256) {
    uint32_t c = h[i * 2] + h[i * 2 + 1];
    if (c) atomicAdd(&histC[i], c);
  }
}

// ---------------- kernel B: parallel suffix-scan bin pick -----------------
// 1024 threads, 4 bins each; LDS inclusive suffix scan; the unique crossing
// thread walks its chunk. Clamps at bin 2048 (kA only counted bins >= 2048).
__global__ void __launch_bounds__(1024) kB(const uint32_t* __restrict__ histC,
                                           uint32_t* sel) {
  __shared__ uint32_t s[1024];
  int t = threadIdx.x;
  uint32_t c0 = histC[t * 4 + 0], c1 = histC[t * 4 + 1];
  uint32_t c2 = histC[t * 4 + 2], c3 = histC[t * 4 + 3];
  s[t] = c0 + c1 + c2 + c3;
  __syncthreads();
  for (int off = 1; off < 1024; off <<= 1) {
    uint32_t add = (t + off < 1024) ? s[t + off] : 0u;
    __syncthreads();
    s[t] += add;
    __syncthreads();
  }
  uint32_t suff = s[t];                               // suffix from bin 4t
  uint32_t above = (t < 1023) ? s[t + 1] : 0u;        // suffix from bin 4t+4
  bool crossing = (suff >= TARGET) && (t == 1023 || above < TARGET);
  if (crossing) {
    uint32_t cum = above;
    uint32_t cc[4] = {c0, c1, c2, c3};
    for (int j = 3; j >= 0; --j) {
      if (cum + cc[j] >= TARGET) { sel[0] = (uint32_t)(t * 4 + j); sel[1] = cum; break; }
      cum += cc[j];
    }
  }
  if (t == 512 && suff < TARGET) {  // degenerate: positives < TARGET
    sel[0] = 2048u; sel[1] = suff - c0;
  }
}

// ---------------- kernel E: compact candidates with key>>20 >= bin --------
__global__ void kE(const float4* __restrict__ cls, int n4,
                   uint32_t* sel, uint32_t* candKey, uint32_t* candIdx) {
  uint32_t bsel = sel[0];
  int stride = gridDim.x * blockDim.x;
  for (int i = blockIdx.x * blockDim.x + threadIdx.x; i < n4; i += stride) {
    float4 v = cls[i];
    float c4[4] = {v.x, v.y, v.z, v.w};
#pragma unroll
    for (int c = 0; c < 4; ++c) {
      uint32_t key = fkey(c4[c]);
      if ((key >> 20) >= bsel) {
        uint32_t pos = atomicAdd(&sel[2], 1u);  // compiler wave-aggregates
        if (pos < CAP) { candKey[pos] = key; candIdx[pos] = (uint32_t)i * 4u + c; }
      }
    }
  }
}

// ---------------- kernel F: refine + sigmoid + bitonic sort + emit --------
__global__ void __launch_bounds__(1024) kF(
    const float* __restrict__ cls, const float* __restrict__ box,
    const int* __restrict__ ph, const int* __restrict__ pw,
    const uint32_t* __restrict__ sel,
    const uint32_t* __restrict__ candKey, const uint32_t* __restrict__ candIdx,
    float* __restrict__ out, float* __restrict__ topScore, float* __restrict__ obox) {
  __shared__ uint32_t fh[1024];
  __shared__ unsigned long long skey[SORTN];
  __shared__ uint32_t scount;
  __shared__ uint32_t TkeyS;
  int tid = threadIdx.x;
  uint32_t n = sel[2]; if (n > CAP) n = CAP;
  uint32_t bsel = sel[0], above = sel[1];

  for (int i = tid; i < 1024; i += 1024) fh[i] = 0u;
  for (int i = tid; i < SORTN; i += 1024) skey[i] = 0ull;
  if (tid == 0) scount = 0u;
  __syncthreads();

  // fine histogram of next 10 key bits (19..10) inside the boundary bin
  for (uint32_t i = tid; i < n; i += 1024u) {
    uint32_t k = candKey[i];
    if ((k >> 20) == bsel) atomicAdd(&fh[(k >> 10) & 1023u], 1u);
  }
  __syncthreads();
  if (tid == 0) {
    uint32_t cum = above; int s = 1023;
    for (; s >= 0; --s) { cum += fh[s]; if (cum >= TARGET) break; }
    if (s < 0) s = 0;
    TkeyS = (bsel << 20) | ((uint32_t)s << 10);
  }
  __syncthreads();
  uint32_t T = TkeyS;

  // select survivors, compute fp32 sigmoid (replicating np 1/(1+exp(-x)))
  for (uint32_t i = tid; i < n; i += 1024u) {
    uint32_t k = candKey[i];
    if (k >= T) {
      uint32_t pos = atomicAdd(&scount, 1u);
      if (pos < SORTN) {
        uint32_t idx = candIdx[i];
        float x = cls[idx];
        float p = 1.0f / (1.0f + expf(-x));
        skey[pos] = ((unsigned long long)__float_as_uint(p) << 32) |
                    (unsigned long long)(uint32_t)(~idx);  // ties: lower idx first
      }
    }
  }
  __syncthreads();

  // bitonic sort, descending by (p_bits, ~idx)
  for (int size = 2; size <= SORTN; size <<= 1) {
    for (int stride = size >> 1; stride > 0; stride >>= 1) {
      __syncthreads();
      for (int t = tid; t < SORTN / 2; t += 1024) {
        int lo = t & (stride - 1);
        int i = ((t - lo) << 1) | lo;
        int j = i + stride;
        unsigned long long a = skey[i], b = skey[j];
        bool desc = ((i & size) == 0);
        if (desc ? (a < b) : (a > b)) { skey[i] = b; skey[j] = a; }
      }
    }
  }
  __syncthreads();

  float W = (float)pw[0], H = (float)ph[0];
  for (int r = tid; r < TOPK; r += 1024) {
    unsigned long long k = skey[r];
    uint32_t idx; float p;
    if (k == 0ull) { idx = 0u; p = 0.0f; }
    else { idx = ~(uint32_t)k; p = __uint_as_float((uint32_t)(k >> 32)); }
    uint32_t label = idx % NUM_CLASSES;
    uint32_t anchor = idx / NUM_CLASSES;
    float b0 = box[anchor * 4u + 0u], b1 = box[anchor * 4u + 1u];
    float b2 = box[anchor * 4u + 2u], b3 = box[anchor * 4u + 3u];
    out[r * 4 + 0] = fminf(fmaxf(b0 / W, 0.0f), 1.0f);
    out[r * 4 + 1] = fminf(fmaxf(b1 / H, 0.0f), 1.0f);
    out[r * 4 + 2] = fminf(fmaxf(b2 / W, 0.0f), 1.0f);
    out[r * 4 + 3] = fminf(fmaxf(b3 / H, 0.0f), 1.0f);
    out[5000 + r] = (float)label;
    topScore[r] = p;
    float off = (float)label * MAX_COORD;  // class-aware NMS offset
    obox[r * 4 + 0] = b0 + off; obox[r * 4 + 1] = b1 + off;
    obox[r * 4 + 2] = b2 + off; obox[r * 4 + 3] = b3 + off;
  }
}

// ---------------- kernel G: IoU suppression bitmasks (j > i) --------------
__global__ void kG(const float* __restrict__ obox, unsigned long long* __restrict__ masks) {
  int i = blockIdx.x;  // row 0..999
  float x1i = obox[i * 4 + 0], y1i = obox[i * 4 + 1];
  float x2i = obox[i * 4 + 2], y2i = obox[i * 4 + 3];
  float ai = (x2i - x1i) * (y2i - y1i);
  for (int base = 0; base < 1024; base += 256) {
    int jj = base + (int)threadIdx.x;
    bool bit = false;
    if (jj < TOPK && jj > i) {
      float x1j = obox[jj * 4 + 0], y1j = obox[jj * 4 + 1];
      float x2j = obox[jj * 4 + 2], y2j = obox[jj * 4 + 3];
      float aj = (x2j - x1j) * (y2j - y1j);
      float ix1 = fmaxf(x1i, x1j), iy1 = fmaxf(y1i, y1j);
      float ix2 = fminf(x2i, x2j), iy2 = fminf(y2i, y2j);
      float iw = fmaxf(ix2 - ix1, 0.0f), ih = fmaxf(iy2 - iy1, 0.0f);
      float inter = iw * ih;
      float iou = inter / (ai + aj - inter + 1e-9f);
      bit = iou > NMS_T;
    }
    unsigned long long m = __ballot(bit);
    if ((threadIdx.x & 63u) == 0u) masks[i * 16 + (jj >> 6)] = m;
  }
}

// ---------------- kernel H: LDS-staged single-wave greedy NMS -------------
__global__ void __launch_bounds__(256) kH(const float* __restrict__ topScore,
                                          const unsigned long long* __restrict__ masks,
                                          float* __restrict__ out) {
  __shared__ unsigned long long lmask[TOPK * 16];
  __shared__ uint32_t nzrow[TOPK];
  __shared__ unsigned long long keepsh[16];
  int t = threadIdx.x;
  for (int i = t; i < TOPK; i += 256) nzrow[i] = 0u;
  if (t < 16) keepsh[t] = 0ull;
  __syncthreads();
  // stage masks (coalesced) + flag nonzero rows
  for (int i = t; i < TOPK * 16; i += 256) {
    unsigned long long m = masks[i];
    lmask[i] = m;
    if (m) atomicOr(&nzrow[i >> 4], 1u);
  }
  // init keep bits from scores via ballot (4 waves cover 256 rows/iter)
  for (int base = 0; base < 1024; base += 256) {
    int r = base + t;
    bool v = (r < TOPK) && (topScore[r] > CONF_T);
    unsigned long long b = __ballot(v);
    if ((t & 63) == 0) keepsh[(base >> 6) + (t >> 6)] = b;
  }
  __syncthreads();
  if (t < 64) {  // single-wave greedy loop, no barriers inside
    unsigned long long kw = (t < 16) ? keepsh[t] : 0ull;
    unsigned long long nzw = 0ull;
    if (t < 16) {
      for (int b = 0; b < 64; ++b) {
        int r = t * 64 + b;
        if (r < TOPK && nzrow[r]) nzw |= 1ull << b;
      }
    }
    for (int w = 0; w < 16; ++w) {
      unsigned long long cur = __shfl(kw, w) & __shfl(nzw, w);
      while (cur) {
        int b = __ffsll((long long)cur) - 1;
        int i = w * 64 + b;
        if (t < 16) kw &= ~lmask[i * 16 + t];  // row i suppresses only j > i
        unsigned long long nk = __shfl(kw, w);
        cur = nk & __shfl(nzw, w);
        cur &= (b == 63) ? 0ull : (~0ull << (b + 1));
      }
    }
    if (t < 16) keepsh[t] = kw;
  }
  __syncthreads();
  for (int r = t; r < TOPK; r += 256) {
    bool k = (keepsh[r >> 6] >> (r & 63)) & 1ull;
    float s = topScore[r];
    out[4000 + r] = k ? s : 0.0f;
    out[6000 + r] = k ? 1.0f : 0.0f;
  }
}

extern "C" void kernel_launch(void* const* d_in, const int* in_sizes, int n_in,
                              void* d_out, int out_size, void* d_ws, size_t ws_size,
                              hipStream_t stream) {
  const float* cls = (const float*)d_in[0];  // (1, N, 80) logits
  const float* box = (const float*)d_in[1];  // (1, N, 4)
  const int* ph = (const int*)d_in[2];       // img_h = 1024
  const int* pw = (const int*)d_in[3];       // img_w = 1024
  float* out = (float*)d_out;                // [boxes 4000 | scores 1000 | labels 1000 | keep 1000]
  int n = in_sizes[0];                       // 20,971,520 (divisible by 4)

  uint8_t* w = (uint8_t*)d_ws;
  uint32_t* histC   = (uint32_t*)(w);                          // 16 KB
  uint32_t* sel     = (uint32_t*)(w + 16384);                  // 64 B
  uint32_t* candKey = (uint32_t*)(w + 20480);                  // CAP*4
  uint32_t* candIdx = (uint32_t*)(w + 20480 + (size_t)CAP * 4);
  float*    topScore= (float*)   (w + 20480 + (size_t)CAP * 8);          // 4 KB
  float*    obox    = (float*)   (w + 20480 + (size_t)CAP * 8 + 4096);   // 16 KB
  unsigned long long* masks = (unsigned long long*)
                             (w + 20480 + (size_t)CAP * 8 + 4096 + 16384); // 128 KB

  kz<<<1, 1024, 0, stream>>>(histC, sel);
  kA<<<2048, 256, 0, stream>>>((const float4*)cls, n / 4, histC);
  kB<<<1, 1024, 0, stream>>>(histC, sel);
  kE<<<2048, 256, 0, stream>>>((const float4*)cls, n / 4, sel, candKey, candIdx);
  kF<<<1, 1024, 0, stream>>>(cls, box, ph, pw, sel, candKey, candIdx, out, topScore, obox);
  kG<<<TOPK, 256, 0, stream>>>(obox, masks);
  kH<<<1, 256, 0, stream>>>(topScore, masks, out);
}